// Round 6
// baseline (990.400 us; speedup 1.0000x reference)
//
#include <hip/hip_runtime.h>
#include <hip/hip_bf16.h>

#define VSZ   32000
#define EMBD  512
#define HIDD  1024
#define BB    64
#define TSEQ  512
#define G4    4096

typedef short bf16x8 __attribute__((ext_vector_type(8)));
typedef float f32x4  __attribute__((ext_vector_type(4)));

__device__ __forceinline__ float sigmoid_f(float x){ return 1.0f/(1.0f+__expf(-x)); }
__device__ __forceinline__ float fast_tanh(float x){
  float e = __expf(2.0f*x);
  return 1.0f - 2.0f*__builtin_amdgcn_rcpf(e + 1.0f);
}
__device__ __forceinline__ short f2bfs(float x){
  unsigned u = __float_as_uint(x);
  unsigned r = (u + 0x7FFFu + ((u>>16)&1u)) >> 16;
  return (short)r;
}
// packed pair: lo half = bf16(a), hi half = bf16(b) -- single HW instr on gfx950
__device__ __forceinline__ unsigned cvtpk(float a, float b){
  unsigned r;
  asm("v_cvt_pk_bf16_f32 %0, %1, %2" : "=v"(r) : "v"(a), "v"(b));
  return r;
}
__device__ __forceinline__ bf16x8 cvt8(float4 a, float4 b){
  union { unsigned u[4]; bf16x8 v; } o;
  o.u[0]=cvtpk(a.x,a.y); o.u[1]=cvtpk(a.z,a.w);
  o.u[2]=cvtpk(b.x,b.y); o.u[3]=cvtpk(b.z,b.w);
  return o.v;
}
__device__ __forceinline__ float wave_sum(float x){
  #pragma unroll
  for (int off=32; off>0; off>>=1) x += __shfl_xor(x, off);
  return x;
}
__device__ __forceinline__ float wave_max(float x){
  #pragma unroll
  for (int off=32; off>0; off>>=1) x = fmaxf(x, __shfl_xor(x, off));
  return x;
}

// ---------------- pack Wk -> plain bf16 row-major ----------------
__global__ __launch_bounds__(256) void k_pack(const float* __restrict__ Wk,
                                              short* __restrict__ dst){
  int id = blockIdx.x*256 + threadIdx.x;   // 131072 groups of 8
  const float4* s = (const float4*)(Wk + (size_t)id*8);
  *(bf16x8*)(dst + (size_t)id*8) = cvt8(s[0], s[1]);
}

// ---------------- prep: x_bf16[:,2560:3584] = bf16(h) ----------------
__global__ __launch_bounds__(256) void k_prep_h(const float* __restrict__ h,
                                                short* __restrict__ xb){
  int id = blockIdx.x*256 + threadIdx.x;     // 8192
  int b = id >> 7, d = (id & 127)*8;
  const float4* s = (const float4*)(h + (size_t)b*HIDD + d);
  *(bf16x8*)(xb + (size_t)b*3584 + 2560 + d) = cvt8(s[0], s[1]);
}

// ---------------- prep: x_bf16[:,0:2560] = bf16(emb|ctxe|ctxb), emb gathered ----------------
__global__ __launch_bounds__(256) void k_prep_x2(const float* __restrict__ tab,
                                                 const int* __restrict__ y,
                                                 const float* __restrict__ ctxe,
                                                 const float* __restrict__ ctxb,
                                                 short* __restrict__ xb){
  int id = blockIdx.x*256 + threadIdx.x;     // 20480
  if (id >= 64*320) return;
  int b = id / 320, off = (id % 320)*8;
  const float* src;
  if (off < 512)        src = tab  + (size_t)y[b]*EMBD + off;
  else if (off < 1536)  src = ctxe + (size_t)b*HIDD + (off-512);
  else                  src = ctxb + (size_t)b*HIDD + (off-1536);
  float4 f0 = ((const float4*)src)[0], f1 = ((const float4*)src)[1];
  *(bf16x8*)(xb + (size_t)b*3584 + off) = cvt8(f0, f1);
}

// ---------------- generic M=64 MFMA GEMM with K-split partials ----------------
__global__ __launch_bounds__(256) void k_mm64(
    const short* __restrict__ A0, int lda0, const float* __restrict__ B0, int ldb0, int K0, float* __restrict__ out0, int ldo0,
    const short* __restrict__ A1, int lda1, const float* __restrict__ B1, int ldb1, int K1, float* __restrict__ out1, int ldo1){
  const short* A; const float* B; float* out; int lda, ldb, K, ldo;
  if (blockIdx.z == 0){ A=A0; B=B0; out=out0; lda=lda0; ldb=ldb0; K=K0; ldo=ldo0; }
  else                { A=A1; B=B1; out=out1; lda=lda1; ldb=ldb1; K=K1; ldo=ldo1; }
  int tid = threadIdx.x, l = tid & 63, w = tid >> 6;
  int l15 = l & 15, l4 = l >> 4;
  int n0 = blockIdx.x*256 + w*64;
  int kper = K / gridDim.y;
  int dbeg = blockIdx.y * kper, dend = dbeg + kper;
  f32x4 acc[4][4];
  #pragma unroll
  for (int i=0;i<4;i++)
    #pragma unroll
    for (int j=0;j<4;j++)
      #pragma unroll
      for (int r=0;r<4;r++) acc[i][j][r]=0.f;
  for (int d0=dbeg; d0<dend; d0+=32){
    bf16x8 af[4];
    #pragma unroll
    for (int ms=0; ms<4; ms++)
      af[ms] = *(const bf16x8*)(A + (size_t)(ms*16 + l15)*lda + d0 + l4*8);
    bf16x8 bfr[4];
    #pragma unroll
    for (int ni=0; ni<4; ni++){
      const float* bp = B + (size_t)(n0 + ni*16 + l15)*ldb + d0 + l4*8;
      float4 f0 = ((const float4*)bp)[0], f1 = ((const float4*)bp)[1];
      bfr[ni] = cvt8(f0, f1);
    }
    #pragma unroll
    for (int ms=0; ms<4; ms++)
      #pragma unroll
      for (int ni=0; ni<4; ni++)
        acc[ms][ni] = __builtin_amdgcn_mfma_f32_16x16x32_bf16(af[ms], bfr[ni], acc[ms][ni], 0,0,0);
  }
  float* op = out + (size_t)blockIdx.y * 64 * ldo;
  #pragma unroll
  for (int ms=0; ms<4; ms++)
    #pragma unroll
    for (int ni=0; ni<4; ni++)
      #pragma unroll
      for (int r=0; r<4; r++){
        int m = ms*16 + l4*4 + r;
        op[(size_t)m*ldo + n0 + ni*16 + l15] = acc[ms][ni][r];
      }
}

// ---------------- K3: energy GEMM, LDS-free / barrier-free ----------------
// 2048 blocks x 512 thr. BM=128 (t), BN=256 (a), K=1024. 8 waves = 2(wr) x 4(wc),
// each 64x64. A: f32 keys direct->reg->cvt_pk. B: bf16 pk direct->reg.
// XCD-chunked: xcd=wg&7; per XCD one att at a time (B 2MB L2-resident); 4 n-blocks
// of an M-tile adjacent for A L2 reuse. Fused tanh/v epilogue -> 4 N-partials.
__global__ __launch_bounds__(512,2) void k_energy(
    const float* __restrict__ enc, const float* __restrict__ bwd,
    const short* __restrict__ pke, const short* __restrict__ pkb,
    const float* __restrict__ qpe, const float* __restrict__ qpb,  // [2][64][1024] partials
    const float* __restrict__ ve, const float* __restrict__ vb,
    float* __restrict__ ep_out){                                   // [att][4][64][512]
  __shared__ float ebuf[8][64];

  int wg = blockIdx.x;
  int xcd = wg & 7, idx = wg >> 3;      // idx 0..255
  int att = idx >> 7;
  int r7  = idx & 127;
  int mtl = r7 >> 2, n = r7 & 3;        // 32 M-tiles, 4 n-blocks per xcd per att
  int gmt = xcd*32 + mtl;               // 0..255
  int b = gmt >> 2, t0 = (gmt & 3)*128;

  const float* keys = att ? bwd : enc;
  const short* pk   = att ? pkb : pke;
  const float* qp   = att ? qpb : qpe;
  const float* v    = att ? vb  : ve;

  int tid = threadIdx.x, l = tid & 63, w = tid >> 6;
  int l15 = l & 15, l4 = l >> 4;
  int wr = w >> 2, wc = w & 3;
  int m0 = t0 + wr*64;
  int n0 = n*256 + wc*64;

  const float* pA[4];
  const short* pB[4];
  #pragma unroll
  for (int ms=0; ms<4; ms++)
    pA[ms] = keys + ((size_t)b*TSEQ + m0 + ms*16 + l15)*1024 + l4*8;
  #pragma unroll
  for (int ni=0; ni<4; ni++)
    pB[ni] = pk + (size_t)(n0 + ni*16 + l15)*1024 + l4*8;

  f32x4 acc[4][4];
  #pragma unroll
  for (int i=0;i<4;i++)
    #pragma unroll
    for (int j=0;j<4;j++)
      #pragma unroll
      for (int r=0;r<4;r++) acc[i][j][r]=0.f;

  #pragma unroll 8
  for (int d0=0; d0<1024; d0+=32){
    bf16x8 af[4], bf[4];
    #pragma unroll
    for (int ms=0; ms<4; ms++){
      float4 x = *(const float4*)(pA[ms] + d0);
      float4 y = *(const float4*)(pA[ms] + d0 + 4);
      af[ms] = cvt8(x, y);
    }
    #pragma unroll
    for (int ni=0; ni<4; ni++)
      bf[ni] = *(const bf16x8*)(pB[ni] + d0);
    #pragma unroll
    for (int ms=0; ms<4; ms++)
      #pragma unroll
      for (int ni=0; ni<4; ni++)
        acc[ms][ni] = __builtin_amdgcn_mfma_f32_16x16x32_bf16(af[ms], bf[ni], acc[ms][ni], 0,0,0);
  }

  // epilogue: partial e over this wave's 64 a's
  float qv[4], vv[4];
  #pragma unroll
  for (int ni=0; ni<4; ni++){
    int a = n0 + ni*16 + l15;
    qv[ni] = qp[(size_t)b*HIDD + a] + qp[65536 + (size_t)b*HIDD + a];
    vv[ni] = v[a];
  }
  float es[16];
  #pragma unroll
  for (int ms=0; ms<4; ms++)
    #pragma unroll
    for (int r=0; r<4; r++){
      float s = 0.f;
      #pragma unroll
      for (int ni=0; ni<4; ni++)
        s += vv[ni]*fast_tanh(qv[ni] + acc[ms][ni][r]);
      es[ms*4+r] = s;
    }
  #pragma unroll
  for (int i=0;i<16;i++){
    float x = es[i];
    x += __shfl_xor(x,1); x += __shfl_xor(x,2);
    x += __shfl_xor(x,4); x += __shfl_xor(x,8);
    es[i] = x;
  }
  if (l15 == 0){
    #pragma unroll
    for (int ms=0; ms<4; ms++)
      #pragma unroll
      for (int r=0; r<4; r++)
        ebuf[w][ms*16 + l4*4 + r] = es[ms*4+r];
  }
  __syncthreads();
  if (tid < 128){
    int wr2 = tid >> 6, m = tid & 63;
    float s = ebuf[wr2*4+0][m] + ebuf[wr2*4+1][m] + ebuf[wr2*4+2][m] + ebuf[wr2*4+3][m];
    ep_out[(((size_t)att*4 + n)*BB + b)*TSEQ + t0 + tid] = s;
  }
}

// ---------------- K4: softmax over T (sums 4 N-partials, applies mask) ----------------
__global__ __launch_bounds__(256) void k_softmax_t(const float* __restrict__ ep,
                                                   const int* __restrict__ mask,
                                                   float* __restrict__ att_e,
                                                   float* __restrict__ att_b){
  int b = blockIdx.x, att = blockIdx.y;
  float* e = (att ? att_b : att_e) + (size_t)b*TSEQ;
  __shared__ float red[8];
  int tid = threadIdx.x, lane = tid & 63, w = tid >> 6;
  float v0 = 0.f, v1 = 0.f;
  #pragma unroll
  for (int i=0;i<4;i++){
    const float* p = ep + (((size_t)att*4 + i)*BB + b)*TSEQ;
    v0 += p[tid]; v1 += p[tid+256];
  }
  if (att==0){
    if (mask[(size_t)b*TSEQ + tid]==0)      v0 = -3.4e38f;
    if (mask[(size_t)b*TSEQ + tid+256]==0)  v1 = -3.4e38f;
  }
  float m = wave_max(fmaxf(v0, v1));
  if (lane==0) red[w] = m;
  __syncthreads();
  m = fmaxf(fmaxf(red[0],red[1]), fmaxf(red[2],red[3]));
  float x0 = __expf(v0-m), x1 = __expf(v1-m);
  float s = wave_sum(x0+x1);
  if (lane==0) red[4+w] = s;
  __syncthreads();
  s = red[4]+red[5]+red[6]+red[7];
  float inv = 1.0f/s;
  e[tid] = x0*inv; e[tid+256] = x1*inv;
}

// ---------------- K5: context = attn @ keys ----------------
__global__ __launch_bounds__(256) void k_ctx(const float* __restrict__ enc,
                                             const float* __restrict__ bwdst,
                                             const float* __restrict__ att_e,
                                             const float* __restrict__ att_b,
                                             float* __restrict__ ctxp){
  int b = blockIdx.x, sel = blockIdx.y, s = blockIdx.z;
  const float* keys = (sel ? bwdst : enc) + ((size_t)b*TSEQ + s*64)*1024;
  const float* att  = (sel ? att_b : att_e) + (size_t)b*TSEQ + s*64;
  int tid = threadIdx.x;
  float acc[4] = {0.f,0.f,0.f,0.f};
  for (int t=0;t<64;t++){
    float a = att[t];
    #pragma unroll
    for (int i=0;i<4;i++) acc[i] += a*keys[(size_t)t*1024 + i*256 + tid];
  }
  float* o = ctxp + (((size_t)sel*BB + b)*8 + s)*1024;
  #pragma unroll
  for (int i=0;i<4;i++) o[i*256+tid] = acc[i];
}

__global__ __launch_bounds__(256) void k_ctxred(const float* __restrict__ ctxp,
                                                float* __restrict__ ctx_e,
                                                float* __restrict__ ctx_b){
  int id = blockIdx.x*256 + threadIdx.x;
  int sel = id >> 16; int rem = id & 65535; int b = rem >> 10; int d = rem & 1023;
  const float* p = ctxp + (((size_t)sel*BB + b)*8)*1024 + d;
  float s = 0.f;
  #pragma unroll
  for (int i=0;i<8;i++) s += p[i*1024];
  (sel ? ctx_b : ctx_e)[(size_t)b*HIDD + d] = s;
}

// ---------------- K7: LSTM cell (8-slot partial reduce) + bf16 h_new ----------------
__global__ __launch_bounds__(256) void k_lstm(const float* __restrict__ gp,
                                              const float* __restrict__ b_ih,
                                              const float* __restrict__ b_hh,
                                              const float* __restrict__ c_old,
                                              float* __restrict__ out,
                                              short* __restrict__ hb){
  int id = blockIdx.x*256 + threadIdx.x;    // 65536
  int b = id >> 10, j = id & 1023;
  size_t base = (size_t)b*G4;
  float gs[4];
  #pragma unroll
  for (int g=0; g<4; g++){
    int col = g*1024 + j;
    float s = b_ih[col] + b_hh[col];
    #pragma unroll
    for (int k=0;k<8;k++) s += gp[(size_t)k*(64*G4) + base + col];
    gs[g] = s;
  }
  float ig = sigmoid_f(gs[0]);
  float fg = sigmoid_f(gs[1]);
  float gg = tanhf(gs[2]);
  float og = sigmoid_f(gs[3]);
  float cn = fg*c_old[id] + ig*gg;
  float hn = og*tanhf(cn);
  out[(size_t)BB*VSZ + id] = hn;
  out[(size_t)BB*VSZ + (size_t)BB*HIDD + id] = cn;
  hb[id] = f2bfs(hn);
}

// ---------------- K8: vocab logits via MFMA, N=128/block (250 blocks) ----------------
__global__ __launch_bounds__(256) void k_vocab2(const short* __restrict__ hb,
                                                const float* __restrict__ Wp,
                                                const float* __restrict__ bp,
                                                float* __restrict__ out){
  int tid = threadIdx.x, l = tid & 63, w = tid >> 6;
  int l15 = l & 15, l4 = l >> 4;
  int mh = w >> 1;
  int n0 = blockIdx.x*128 + (w&1)*64;
  f32x4 acc[2][4];
  #pragma unroll
  for (int i=0;i<2;i++)
    #pragma unroll
    for (int j=0;j<4;j++)
      #pragma unroll
      for (int r=0;r<4;r++) acc[i][j][r]=0.f;
  for (int d0=0; d0<1024; d0+=32){
    bf16x8 af[2];
    #pragma unroll
    for (int ms=0; ms<2; ms++)
      af[ms] = *(const bf16x8*)(hb + (size_t)(mh*32 + ms*16 + l15)*1024 + d0 + l4*8);
    bf16x8 bfr[4];
    #pragma unroll
    for (int ni=0; ni<4; ni++){
      const float* bpp = Wp + (size_t)(n0 + ni*16 + l15)*1024 + d0 + l4*8;
      float4 f0 = ((const float4*)bpp)[0], f1 = ((const float4*)bpp)[1];
      bfr[ni] = cvt8(f0, f1);
    }
    #pragma unroll
    for (int ms=0; ms<2; ms++)
      #pragma unroll
      for (int ni=0; ni<4; ni++)
        acc[ms][ni] = __builtin_amdgcn_mfma_f32_16x16x32_bf16(af[ms], bfr[ni], acc[ms][ni], 0,0,0);
  }
  #pragma unroll
  for (int ms=0; ms<2; ms++)
    #pragma unroll
    for (int ni=0; ni<4; ni++)
      #pragma unroll
      for (int r=0; r<4; r++){
        int m = mh*32 + ms*16 + l4*4 + r;
        int n = n0 + ni*16 + l15;
        out[(size_t)m*VSZ + n] = acc[ms][ni][r] + bp[n];
      }
}

// ---------------- K9: p_gen + softmax(V), 1024 threads ----------------
__global__ __launch_bounds__(1024) void k_final(const float* __restrict__ ctxe,
                                                const float* __restrict__ tab,
                                                const int* __restrict__ y,
                                                const float* __restrict__ wc,
                                                const float* __restrict__ wsv,
                                                const float* __restrict__ wy,
                                                const float* __restrict__ pgb,
                                                float* __restrict__ out,
                                                float* __restrict__ pgen_ws){
  __shared__ float red[32];
  int b = blockIdx.x, tid = threadIdx.x, lane = tid & 63, w = tid >> 6;
  const float* hn = out + (size_t)BB*VSZ + (size_t)b*HIDD;
  float acc = ctxe[(size_t)b*HIDD + tid]*wc[tid] + hn[tid]*wsv[tid];
  if (tid < 512) acc += tab[(size_t)y[b]*EMBD + tid]*wy[tid];
  acc = wave_sum(acc);
  if (lane==0) red[w] = acc;
  __syncthreads();
  float s0 = pgb[0];
  #pragma unroll
  for (int i=0;i<16;i++) s0 += red[i];
  float pg = sigmoid_f(s0);
  if (tid==0) pgen_ws[b] = pg;
  __syncthreads();

  float* row = out + (size_t)b*VSZ;
  float m = -3.4e38f;
  for (int i=tid;i<VSZ;i+=1024) m = fmaxf(m, row[i]);
  m = wave_max(m);
  if (lane==0) red[w] = m;
  __syncthreads();
  #pragma unroll
  for (int i=0;i<16;i++) m = fmaxf(m, red[i]);
  float s = 0.f;
  for (int i=tid;i<VSZ;i+=1024) s += __expf(row[i]-m);
  s = wave_sum(s);
  if (lane==0) red[16+w] = s;
  __syncthreads();
  float tot = 0.f;
  #pragma unroll
  for (int i=0;i<16;i++) tot += red[16+i];
  float scale = pg / tot;
  for (int i=tid;i<VSZ;i+=1024) row[i] = __expf(row[i]-m)*scale;
}

// ---------------- K10: pointer scatter ----------------
__global__ __launch_bounds__(256) void k_scatter(const int* __restrict__ src_ids,
                                                 const float* __restrict__ att_e,
                                                 const float* __restrict__ pgen_ws,
                                                 float* __restrict__ out){
  int id = blockIdx.x*256 + threadIdx.x;
  int b = id >> 9;
  float pg = pgen_ws[b];
  int sid = src_ids[id];
  float contrib = (1.0f - pg) * att_e[id] * (sid < VSZ ? 1.0f : 0.0f);
  int safe = sid < VSZ-1 ? sid : VSZ-1;
  atomicAdd(&out[(size_t)b*VSZ + safe], contrib);
}

extern "C" void kernel_launch(void* const* d_in, const int* in_sizes, int n_in,
                              void* d_out, int out_size, void* d_ws, size_t ws_size,
                              hipStream_t stream){
  const int*   y     = (const int*)d_in[0];
  const float* h     = (const float*)d_in[1];
  const float* c     = (const float*)d_in[2];
  const float* enc   = (const float*)d_in[3];
  const float* bwd   = (const float*)d_in[4];
  const int*   sids  = (const int*)d_in[5];
  const int*   smask = (const int*)d_in[6];
  const float* tab   = (const float*)d_in[7];
  const float* W_ih  = (const float*)d_in[8];
  const float* W_hh  = (const float*)d_in[9];
  const float* b_ih  = (const float*)d_in[10];
  const float* b_hh  = (const float*)d_in[11];
  const float* Wq_e  = (const float*)d_in[12];
  const float* Wk_e  = (const float*)d_in[13];
  const float* v_e   = (const float*)d_in[14];
  const float* Wq_b  = (const float*)d_in[15];
  const float* Wk_b  = (const float*)d_in[16];
  const float* v_b   = (const float*)d_in[17];
  const float* Wp    = (const float*)d_in[18];
  const float* bp    = (const float*)d_in[19];
  const float* wc    = (const float*)d_in[20];
  const float* wsv   = (const float*)d_in[21];
  const float* wy    = (const float*)d_in[22];
  const float* pgb   = (const float*)d_in[23];
  float* out = (float*)d_out;

  float* W = (float*)d_ws;
  float* ws_qpe  = W; W += 2*BB*HIDD;        // qproj partials
  float* ws_qpb  = W; W += 2*BB*HIDD;
  float* ws_ep   = W; W += 2*8*BB*TSEQ;      // energy partials (only [2][4][64][512] used)
  float* ws_atte = W; W += BB*TSEQ;
  float* ws_attb = W; W += BB*TSEQ;
  float* ws_ctxe = W; W += BB*HIDD;
  float* ws_ctxb = W; W += BB*HIDD;
  float* ws_ctxp = W; W += 2*BB*8*1024;      // 1048576
  float* ws_pgen = W; W += 64;
  float* ws_gp   = W; W += 8*BB*G4;          // 2097152 (8 K-split slots)
  short* xb      = (short*)W; W += (BB*3584)/2;
  short* hb      = (short*)W; W += (BB*HIDD)/2;
  short* pk_e    = (short*)W; W += (HIDD*HIDD)/2;   // bf16 Wk_e (row-major)
  short* pk_b    = (short*)W; W += (HIDD*HIDD)/2;

  k_pack<<<512, 256, 0, stream>>>(Wk_e, pk_e);
  k_pack<<<512, 256, 0, stream>>>(Wk_b, pk_b);
  k_prep_h<<<32, 256, 0, stream>>>(h, xb);
  k_mm64<<<dim3(4,2,2), 256, 0, stream>>>(
      xb+2560, 3584, Wq_e, 1024, 1024, ws_qpe, 1024,
      xb+2560, 3584, Wq_b, 1024, 1024, ws_qpb, 1024);
  k_energy<<<2048, 512, 0, stream>>>(enc, bwd, pk_e, pk_b,
      ws_qpe, ws_qpb, v_e, v_b, ws_ep);
  k_softmax_t<<<dim3(BB,2), 256, 0, stream>>>(ws_ep, smask, ws_atte, ws_attb);
  k_ctx<<<dim3(BB,2,8), 256, 0, stream>>>(enc, bwd, ws_atte, ws_attb, ws_ctxp);
  k_ctxred<<<512, 256, 0, stream>>>(ws_ctxp, ws_ctxe, ws_ctxb);
  k_prep_x2<<<80, 256, 0, stream>>>(tab, y, ws_ctxe, ws_ctxb, xb);
  k_mm64<<<dim3(16,4,2), 256, 0, stream>>>(
      xb,      3584, W_ih, 2560, 2560, ws_gp,             G4,
      xb+2560, 3584, W_hh, 1024, 1024, ws_gp + 4*BB*G4,   G4);
  k_lstm<<<256, 256, 0, stream>>>(ws_gp, b_ih, b_hh, c, out, hb);
  k_vocab2<<<250, 256, 0, stream>>>(hb, Wp, bp, out);
  k_final<<<BB, 1024, 0, stream>>>(ws_ctxe, tab, y, wc, wsv, wy, pgb, out, ws_pgen);
  k_scatter<<<128, 256, 0, stream>>>(sids, ws_atte, ws_pgen, out);
}

// Round 7
// 400.187 us; speedup vs baseline: 2.4748x; 2.4748x over previous
//
#include <hip/hip_runtime.h>
#include <hip/hip_bf16.h>

#define VSZ   32000
#define EMBD  512
#define HIDD  1024
#define BB    64
#define TSEQ  512
#define G4    4096

typedef short bf16x8 __attribute__((ext_vector_type(8)));
typedef float f32x4  __attribute__((ext_vector_type(4)));
typedef float f32x16 __attribute__((ext_vector_type(16)));

__device__ __forceinline__ float sigmoid_f(float x){ return 1.0f/(1.0f+__expf(-x)); }
__device__ __forceinline__ float fast_tanh(float x){
  float e = __expf(2.0f*x);
  return 1.0f - 2.0f*__builtin_amdgcn_rcpf(e + 1.0f);
}
__device__ __forceinline__ short f2bfs(float x){
  unsigned u = __float_as_uint(x);
  unsigned r = (u + 0x7FFFu + ((u>>16)&1u)) >> 16;
  return (short)r;
}
// single-instr packed f32x2 -> bf16x2 (RNE), gfx950
__device__ __forceinline__ unsigned cvtpk(float a, float b){
  unsigned r;
  asm("v_cvt_pk_bf16_f32 %0, %1, %2" : "=v"(r) : "v"(a), "v"(b));
  return r;
}
__device__ __forceinline__ bf16x8 cvt8(float4 a, float4 b){
  union { unsigned u[4]; bf16x8 v; } o;
  o.u[0]=cvtpk(a.x,a.y); o.u[1]=cvtpk(a.z,a.w);
  o.u[2]=cvtpk(b.x,b.y); o.u[3]=cvtpk(b.z,b.w);
  return o.v;
}
__device__ __forceinline__ float wave_sum(float x){
  #pragma unroll
  for (int off=32; off>0; off>>=1) x += __shfl_xor(x, off);
  return x;
}
__device__ __forceinline__ float wave_max(float x){
  #pragma unroll
  for (int off=32; off>0; off>>=1) x = fmaxf(x, __shfl_xor(x, off));
  return x;
}

// ---------------- pack Wk into MFMA B-fragment order, f32 -> bf16 ----------------
// dst[((nt*64 + s)*64 + l)*8 + j] = Wk[nt*32 + (l&31)][s*16 + (l>>5)*8 + j]
__global__ __launch_bounds__(256) void k_pack(const float* __restrict__ Wk,
                                              short* __restrict__ dst){
  int id = blockIdx.x*256 + threadIdx.x;   // 131072 = 32nt * 64s * 64l
  int l = id & 63, s = (id>>6) & 63, nt = id >> 12;
  const float* src = Wk + (size_t)(nt*32 + (l&31))*1024 + s*16 + (l>>5)*8;
  float4 f0 = ((const float4*)src)[0], f1 = ((const float4*)src)[1];
  *(bf16x8*)(dst + (size_t)id*8) = cvt8(f0, f1);
}

// ---------------- prep: x_bf16[:,2560:3584] = bf16(h) ----------------
__global__ __launch_bounds__(256) void k_prep_h(const float* __restrict__ h,
                                                short* __restrict__ xb){
  int id = blockIdx.x*256 + threadIdx.x;     // 8192
  int b = id >> 7, d = (id & 127)*8;
  const float4* s = (const float4*)(h + (size_t)b*HIDD + d);
  *(bf16x8*)(xb + (size_t)b*3584 + 2560 + d) = cvt8(s[0], s[1]);
}

// ---------------- prep: x_bf16[:,0:2560] = bf16(emb|ctxe|ctxb), emb gathered ----------------
__global__ __launch_bounds__(256) void k_prep_x2(const float* __restrict__ tab,
                                                 const int* __restrict__ y,
                                                 const float* __restrict__ ctxe,
                                                 const float* __restrict__ ctxb,
                                                 short* __restrict__ xb){
  int id = blockIdx.x*256 + threadIdx.x;     // 20480
  if (id >= 64*320) return;
  int b = id / 320, off = (id % 320)*8;
  const float* src;
  if (off < 512)        src = tab  + (size_t)y[b]*EMBD + off;
  else if (off < 1536)  src = ctxe + (size_t)b*HIDD + (off-512);
  else                  src = ctxb + (size_t)b*HIDD + (off-1536);
  float4 f0 = ((const float4*)src)[0], f1 = ((const float4*)src)[1];
  *(bf16x8*)(xb + (size_t)b*3584 + off) = cvt8(f0, f1);
}

// ---------------- generic M=64 MFMA GEMM with K-split partials ----------------
__global__ __launch_bounds__(256) void k_mm64(
    const short* __restrict__ A0, int lda0, const float* __restrict__ B0, int ldb0, int K0, float* __restrict__ out0, int ldo0,
    const short* __restrict__ A1, int lda1, const float* __restrict__ B1, int ldb1, int K1, float* __restrict__ out1, int ldo1){
  const short* A; const float* B; float* out; int lda, ldb, K, ldo;
  if (blockIdx.z == 0){ A=A0; B=B0; out=out0; lda=lda0; ldb=ldb0; K=K0; ldo=ldo0; }
  else                { A=A1; B=B1; out=out1; lda=lda1; ldb=ldb1; K=K1; ldo=ldo1; }
  int tid = threadIdx.x, l = tid & 63, w = tid >> 6;
  int l15 = l & 15, l4 = l >> 4;
  int n0 = blockIdx.x*256 + w*64;
  int kper = K / gridDim.y;
  int dbeg = blockIdx.y * kper, dend = dbeg + kper;
  f32x4 acc[4][4];
  #pragma unroll
  for (int i=0;i<4;i++)
    #pragma unroll
    for (int j=0;j<4;j++)
      #pragma unroll
      for (int r=0;r<4;r++) acc[i][j][r]=0.f;
  for (int d0=dbeg; d0<dend; d0+=32){
    bf16x8 af[4];
    #pragma unroll
    for (int ms=0; ms<4; ms++)
      af[ms] = *(const bf16x8*)(A + (size_t)(ms*16 + l15)*lda + d0 + l4*8);
    bf16x8 bfr[4];
    #pragma unroll
    for (int ni=0; ni<4; ni++){
      const float* bp = B + (size_t)(n0 + ni*16 + l15)*ldb + d0 + l4*8;
      float4 f0 = ((const float4*)bp)[0], f1 = ((const float4*)bp)[1];
      bfr[ni] = cvt8(f0, f1);
    }
    #pragma unroll
    for (int ms=0; ms<4; ms++)
      #pragma unroll
      for (int ni=0; ni<4; ni++)
        acc[ms][ni] = __builtin_amdgcn_mfma_f32_16x16x32_bf16(af[ms], bfr[ni], acc[ms][ni], 0,0,0);
  }
  float* op = out + (size_t)blockIdx.y * 64 * ldo;
  #pragma unroll
  for (int ms=0; ms<4; ms++)
    #pragma unroll
    for (int ni=0; ni<4; ni++)
      #pragma unroll
      for (int r=0; r<4; r++){
        int m = ms*16 + l4*4 + r;
        op[(size_t)m*ldo + n0 + ni*16 + l15] = acc[ms][ni][r];
      }
}

// ---------------- K3: fused attention energy via MFMA 32x32x16 (round-3 structure
// + 1-step B register prefetch + cvt_pk staging). grid (8 t-tiles, 64 b, 2 att), 512 thr.
__global__ __launch_bounds__(512,2) void k_energy(
    const float* __restrict__ enc, const float* __restrict__ bwd,
    const short* __restrict__ pke, const short* __restrict__ pkb,
    const float* __restrict__ qpe, const float* __restrict__ qpb,  // [2][64][1024] K-split partials
    const float* __restrict__ ve, const float* __restrict__ vb,
    const int* __restrict__ mask,
    float* __restrict__ out_e, float* __restrict__ out_b){
  __shared__ short A_s[2][64*128];          // 2 x 16 KB, XOR-swizzled
  __shared__ float ebuf[8][64];
  int att = blockIdx.z;
  const float* keys = att ? bwd : enc;
  const short* pk   = att ? pkb : pke;
  const float* qp   = att ? qpb : qpe;
  const float* v    = att ? vb  : ve;
  int b = blockIdx.y, t0 = blockIdx.x*64;
  int tid = threadIdx.x;
  int l = tid & 63, w = tid >> 6;
  int lhi = l >> 5, l31 = l & 31;

  // staging: thread (sr = t-row, sf = 16-float chunk) -> 16 bf16 (2 swizzled b128 writes)
  int sr = tid >> 3, sf = tid & 7;
  const float4* ssrc = (const float4*)(keys + ((size_t)(b*TSEQ + t0 + sr))*1024 + sf*16);
  char* swb0 = (char*)A_s + sr*256 + ((sf*32)      ^ ((sr&7)<<4));
  char* swb1 = (char*)A_s + sr*256 + ((sf*32 + 16) ^ ((sr&7)<<4));

  const bf16x8* Bp = ((const bf16x8*)pk) + (size_t)(w*4)*64*64 + l;
  int rb0 = l31*256, rb1 = (l31+32)*256;
  int xorv = (l31&7)<<4, boff = lhi*16;

  f32x16 acc0[4], acc1[4];
  #pragma unroll
  for (int at=0; at<4; at++)
    #pragma unroll
    for (int r=0;r<16;r++){ acc0[at][r]=0.f; acc1[at][r]=0.f; }

  float4 st[4];
  // prologue: stage chunk 0, issue loads for chunk 1
  st[0]=ssrc[0]; st[1]=ssrc[1]; st[2]=ssrc[2]; st[3]=ssrc[3];
  *(bf16x8*)(swb0) = cvt8(st[0], st[1]);
  *(bf16x8*)(swb1) = cvt8(st[2], st[3]);
  __syncthreads();
  st[0]=ssrc[32]; st[1]=ssrc[33]; st[2]=ssrc[34]; st[3]=ssrc[35];

  // B pipeline: bn holds fragments for step s+1
  bf16x8 bn0 = Bp[0*64];
  bf16x8 bn1 = Bp[64*64];
  bf16x8 bn2 = Bp[128*64];
  bf16x8 bn3 = Bp[192*64];

  for (int c=0; c<8; ++c){
    const char* base = (const char*)A_s + (c&1)*16384;
    #pragma unroll
    for (int ss=0; ss<8; ++ss){
      int s = c*8 + ss;
      bf16x8 b0 = bn0, b1 = bn1, b2 = bn2, b3 = bn3;
      int sp1 = (s < 63) ? s+1 : 63;      // harmless reload on last step
      bn0 = Bp[(  0 + sp1)*64];
      bn1 = Bp[( 64 + sp1)*64];
      bn2 = Bp[(128 + sp1)*64];
      bn3 = Bp[(192 + sp1)*64];
      int off = ((ss*32 + boff) ^ xorv);
      bf16x8 a0 = *(const bf16x8*)(base + rb0 + off);
      bf16x8 a1 = *(const bf16x8*)(base + rb1 + off);
      acc0[0] = __builtin_amdgcn_mfma_f32_32x32x16_bf16(a0, b0, acc0[0], 0,0,0);
      acc1[0] = __builtin_amdgcn_mfma_f32_32x32x16_bf16(a1, b0, acc1[0], 0,0,0);
      acc0[1] = __builtin_amdgcn_mfma_f32_32x32x16_bf16(a0, b1, acc0[1], 0,0,0);
      acc1[1] = __builtin_amdgcn_mfma_f32_32x32x16_bf16(a1, b1, acc1[1], 0,0,0);
      acc0[2] = __builtin_amdgcn_mfma_f32_32x32x16_bf16(a0, b2, acc0[2], 0,0,0);
      acc1[2] = __builtin_amdgcn_mfma_f32_32x32x16_bf16(a1, b2, acc1[2], 0,0,0);
      acc0[3] = __builtin_amdgcn_mfma_f32_32x32x16_bf16(a0, b3, acc0[3], 0,0,0);
      acc1[3] = __builtin_amdgcn_mfma_f32_32x32x16_bf16(a1, b3, acc1[3], 0,0,0);
    }
    if (c < 7){
      // write-late (T14): st holds chunk c+1, loaded one chunk ago
      char* dst = (char*)A_s + ((c+1)&1)*16384;
      *(bf16x8*)(dst + (swb0 - (char*)A_s)) = cvt8(st[0], st[1]);
      *(bf16x8*)(dst + (swb1 - (char*)A_s)) = cvt8(st[2], st[3]);
      if (c < 6){
        const float4* s4 = ssrc + (c+2)*32;
        st[0]=s4[0]; st[1]=s4[1]; st[2]=s4[2]; st[3]=s4[3];
      }
    }
    __syncthreads();
  }

  // fused tanh + v-weighted partial reduction over this wave's 128 a's
  float ep0[16], ep1[16];
  #pragma unroll
  for (int r=0;r<16;r++){ ep0[r]=0.f; ep1[r]=0.f; }
  #pragma unroll
  for (int at=0; at<4; at++){
    int a = w*128 + at*32 + l31;
    float qv = qp[(size_t)b*HIDD + a] + qp[65536 + (size_t)b*HIDD + a];
    float vv = v[a];
    #pragma unroll
    for (int r=0;r<16;r++){
      ep0[r] += vv * fast_tanh(qv + acc0[at][r]);
      ep1[r] += vv * fast_tanh(qv + acc1[at][r]);
    }
  }
  #pragma unroll
  for (int r=0;r<16;r++){
    float x = ep0[r];
    x += __shfl_xor(x,1); x += __shfl_xor(x,2); x += __shfl_xor(x,4);
    x += __shfl_xor(x,8); x += __shfl_xor(x,16);
    ep0[r] = x;
    float y = ep1[r];
    y += __shfl_xor(y,1); y += __shfl_xor(y,2); y += __shfl_xor(y,4);
    y += __shfl_xor(y,8); y += __shfl_xor(y,16);
    ep1[r] = y;
  }
  if (l31 == 0){
    #pragma unroll
    for (int r=0;r<16;r++){
      int t = (r&3) + 8*(r>>2) + 4*lhi;
      ebuf[w][t]      = ep0[r];
      ebuf[w][t + 32] = ep1[r];
    }
  }
  __syncthreads();
  if (tid < 64){
    float s = 0.f;
    #pragma unroll
    for (int ww=0; ww<8; ww++) s += ebuf[ww][tid];
    int t = t0 + tid;
    if (att==0 && mask[(size_t)b*TSEQ + t]==0) s = -3.4e38f;
    (att ? out_b : out_e)[(size_t)b*TSEQ + t] = s;
  }
}

// ---------------- K4: softmax over T, in place ----------------
__global__ __launch_bounds__(256) void k_softmax_t(float* __restrict__ e_enc,
                                                   float* __restrict__ e_bwd){
  float* e = (blockIdx.y==0 ? e_enc : e_bwd) + (size_t)blockIdx.x*TSEQ;
  __shared__ float red[8];
  int tid = threadIdx.x, lane = tid & 63, w = tid >> 6;
  float v0 = e[tid], v1 = e[tid+256];
  float m = wave_max(fmaxf(v0, v1));
  if (lane==0) red[w] = m;
  __syncthreads();
  m = fmaxf(fmaxf(red[0],red[1]), fmaxf(red[2],red[3]));
  float x0 = __expf(v0-m), x1 = __expf(v1-m);
  float s = wave_sum(x0+x1);
  if (lane==0) red[4+w] = s;
  __syncthreads();
  s = red[4]+red[5]+red[6]+red[7];
  float inv = 1.0f/s;
  e[tid] = x0*inv; e[tid+256] = x1*inv;
}

// ---------------- K5: context = attn @ keys ----------------
__global__ __launch_bounds__(256) void k_ctx(const float* __restrict__ enc,
                                             const float* __restrict__ bwdst,
                                             const float* __restrict__ att_e,
                                             const float* __restrict__ att_b,
                                             float* __restrict__ ctxp){
  int b = blockIdx.x, sel = blockIdx.y, s = blockIdx.z;
  const float* keys = (sel ? bwdst : enc) + ((size_t)b*TSEQ + s*64)*1024;
  const float* att  = (sel ? att_b : att_e) + (size_t)b*TSEQ + s*64;
  int tid = threadIdx.x;
  float acc[4] = {0.f,0.f,0.f,0.f};
  for (int t=0;t<64;t++){
    float a = att[t];
    #pragma unroll
    for (int i=0;i<4;i++) acc[i] += a*keys[(size_t)t*1024 + i*256 + tid];
  }
  float* o = ctxp + (((size_t)sel*BB + b)*8 + s)*1024;
  #pragma unroll
  for (int i=0;i<4;i++) o[i*256+tid] = acc[i];
}

__global__ __launch_bounds__(256) void k_ctxred(const float* __restrict__ ctxp,
                                                float* __restrict__ ctx_e,
                                                float* __restrict__ ctx_b){
  int id = blockIdx.x*256 + threadIdx.x;
  int sel = id >> 16; int rem = id & 65535; int b = rem >> 10; int d = rem & 1023;
  const float* p = ctxp + (((size_t)sel*BB + b)*8)*1024 + d;
  float s = 0.f;
  #pragma unroll
  for (int i=0;i<8;i++) s += p[i*1024];
  (sel ? ctx_b : ctx_e)[(size_t)b*HIDD + d] = s;
}

// ---------------- K7: LSTM cell (8-slot partial reduce) + bf16 h_new ----------------
__global__ __launch_bounds__(256) void k_lstm(const float* __restrict__ gp,
                                              const float* __restrict__ b_ih,
                                              const float* __restrict__ b_hh,
                                              const float* __restrict__ c_old,
                                              float* __restrict__ out,
                                              short* __restrict__ hb){
  int id = blockIdx.x*256 + threadIdx.x;    // 65536
  int b = id >> 10, j = id & 1023;
  size_t base = (size_t)b*G4;
  float gs[4];
  #pragma unroll
  for (int g=0; g<4; g++){
    int col = g*1024 + j;
    float s = b_ih[col] + b_hh[col];
    #pragma unroll
    for (int k=0;k<8;k++) s += gp[(size_t)k*(64*G4) + base + col];
    gs[g] = s;
  }
  float ig = sigmoid_f(gs[0]);
  float fg = sigmoid_f(gs[1]);
  float gg = tanhf(gs[2]);
  float og = sigmoid_f(gs[3]);
  float cn = fg*c_old[id] + ig*gg;
  float hn = og*tanhf(cn);
  out[(size_t)BB*VSZ + id] = hn;
  out[(size_t)BB*VSZ + (size_t)BB*HIDD + id] = cn;
  hb[id] = f2bfs(hn);
}

// ---------------- K8: vocab logits via MFMA, N=128/block (250 blocks) ----------------
__global__ __launch_bounds__(256) void k_vocab2(const short* __restrict__ hb,
                                                const float* __restrict__ Wp,
                                                const float* __restrict__ bp,
                                                float* __restrict__ out){
  int tid = threadIdx.x, l = tid & 63, w = tid >> 6;
  int l15 = l & 15, l4 = l >> 4;
  int mh = w >> 1;
  int n0 = blockIdx.x*128 + (w&1)*64;
  f32x4 acc[2][4];
  #pragma unroll
  for (int i=0;i<2;i++)
    #pragma unroll
    for (int j=0;j<4;j++)
      #pragma unroll
      for (int r=0;r<4;r++) acc[i][j][r]=0.f;
  for (int d0=0; d0<1024; d0+=32){
    bf16x8 af[2];
    #pragma unroll
    for (int ms=0; ms<2; ms++)
      af[ms] = *(const bf16x8*)(hb + (size_t)(mh*32 + ms*16 + l15)*1024 + d0 + l4*8);
    bf16x8 bfr[4];
    #pragma unroll
    for (int ni=0; ni<4; ni++){
      const float* bpp = Wp + (size_t)(n0 + ni*16 + l15)*1024 + d0 + l4*8;
      float4 f0 = ((const float4*)bpp)[0], f1 = ((const float4*)bpp)[1];
      bfr[ni] = cvt8(f0, f1);
    }
    #pragma unroll
    for (int ms=0; ms<2; ms++)
      #pragma unroll
      for (int ni=0; ni<4; ni++)
        acc[ms][ni] = __builtin_amdgcn_mfma_f32_16x16x32_bf16(af[ms], bfr[ni], acc[ms][ni], 0,0,0);
  }
  #pragma unroll
  for (int ms=0; ms<2; ms++)
    #pragma unroll
    for (int ni=0; ni<4; ni++)
      #pragma unroll
      for (int r=0; r<4; r++){
        int m = mh*32 + ms*16 + l4*4 + r;
        int n = n0 + ni*16 + l15;
        out[(size_t)m*VSZ + n] = acc[ms][ni][r] + bp[n];
      }
}

// ---------------- K9: p_gen + softmax(V), 1024 threads ----------------
__global__ __launch_bounds__(1024) void k_final(const float* __restrict__ ctxe,
                                                const float* __restrict__ tab,
                                                const int* __restrict__ y,
                                                const float* __restrict__ wc,
                                                const float* __restrict__ wsv,
                                                const float* __restrict__ wy,
                                                const float* __restrict__ pgb,
                                                float* __restrict__ out,
                                                float* __restrict__ pgen_ws){
  __shared__ float red[32];
  int b = blockIdx.x, tid = threadIdx.x, lane = tid & 63, w = tid >> 6;
  const float* hn = out + (size_t)BB*VSZ + (size_t)b*HIDD;
  float acc = ctxe[(size_t)b*HIDD + tid]*wc[tid] + hn[tid]*wsv[tid];
  if (tid < 512) acc += tab[(size_t)y[b]*EMBD + tid]*wy[tid];
  acc = wave_sum(acc);
  if (lane==0) red[w] = acc;
  __syncthreads();
  float s0 = pgb[0];
  #pragma unroll
  for (int i=0;i<16;i++) s0 += red[i];
  float pg = sigmoid_f(s0);
  if (tid==0) pgen_ws[b] = pg;
  __syncthreads();

  float* row = out + (size_t)b*VSZ;
  float m = -3.4e38f;
  for (int i=tid;i<VSZ;i+=1024) m = fmaxf(m, row[i]);
  m = wave_max(m);
  if (lane==0) red[w] = m;
  __syncthreads();
  #pragma unroll
  for (int i=0;i<16;i++) m = fmaxf(m, red[i]);
  float s = 0.f;
  for (int i=tid;i<VSZ;i+=1024) s += __expf(row[i]-m);
  s = wave_sum(s);
  if (lane==0) red[16+w] = s;
  __syncthreads();
  float tot = 0.f;
  #pragma unroll
  for (int i=0;i<16;i++) tot += red[16+i];
  float scale = pg / tot;
  for (int i=tid;i<VSZ;i+=1024) row[i] = __expf(row[i]-m)*scale;
}

// ---------------- K10: pointer scatter ----------------
__global__ __launch_bounds__(256) void k_scatter(const int* __restrict__ src_ids,
                                                 const float* __restrict__ att_e,
                                                 const float* __restrict__ pgen_ws,
                                                 float* __restrict__ out){
  int id = blockIdx.x*256 + threadIdx.x;
  int b = id >> 9;
  float pg = pgen_ws[b];
  int sid = src_ids[id];
  float contrib = (1.0f - pg) * att_e[id] * (sid < VSZ ? 1.0f : 0.0f);
  int safe = sid < VSZ-1 ? sid : VSZ-1;
  atomicAdd(&out[(size_t)b*VSZ + safe], contrib);
}

extern "C" void kernel_launch(void* const* d_in, const int* in_sizes, int n_in,
                              void* d_out, int out_size, void* d_ws, size_t ws_size,
                              hipStream_t stream){
  const int*   y     = (const int*)d_in[0];
  const float* h     = (const float*)d_in[1];
  const float* c     = (const float*)d_in[2];
  const float* enc   = (const float*)d_in[3];
  const float* bwd   = (const float*)d_in[4];
  const int*   sids  = (const int*)d_in[5];
  const int*   smask = (const int*)d_in[6];
  const float* tab   = (const float*)d_in[7];
  const float* W_ih  = (const float*)d_in[8];
  const float* W_hh  = (const float*)d_in[9];
  const float* b_ih  = (const float*)d_in[10];
  const float* b_hh  = (const float*)d_in[11];
  const float* Wq_e  = (const float*)d_in[12];
  const float* Wk_e  = (const float*)d_in[13];
  const float* v_e   = (const float*)d_in[14];
  const float* Wq_b  = (const float*)d_in[15];
  const float* Wk_b  = (const float*)d_in[16];
  const float* v_b   = (const float*)d_in[17];
  const float* Wp    = (const float*)d_in[18];
  const float* bp    = (const float*)d_in[19];
  const float* wc    = (const float*)d_in[20];
  const float* wsv   = (const float*)d_in[21];
  const float* wy    = (const float*)d_in[22];
  const float* pgb   = (const float*)d_in[23];
  float* out = (float*)d_out;

  float* W = (float*)d_ws;
  float* ws_qpe  = W; W += 2*BB*HIDD;        // qproj partials (2 K-split slots)
  float* ws_qpb  = W; W += 2*BB*HIDD;
  float* ws_atte = W; W += BB*TSEQ;
  float* ws_attb = W; W += BB*TSEQ;
  float* ws_ctxe = W; W += BB*HIDD;
  float* ws_ctxb = W; W += BB*HIDD;
  float* ws_ctxp = W; W += 2*BB*8*1024;      // 1048576
  float* ws_pgen = W; W += 64;
  float* ws_gp   = W; W += 8*BB*G4;          // 2097152 (8 K-split slots)
  short* xb      = (short*)W; W += (BB*3584)/2;
  short* hb      = (short*)W; W += (BB*HIDD)/2;
  short* pk_e    = (short*)W; W += (HIDD*HIDD)/2;   // fragment-order Wk_e bf16
  short* pk_b    = (short*)W; W += (HIDD*HIDD)/2;

  k_pack<<<512, 256, 0, stream>>>(Wk_e, pk_e);
  k_pack<<<512, 256, 0, stream>>>(Wk_b, pk_b);
  k_prep_h<<<32, 256, 0, stream>>>(h, xb);
  k_mm64<<<dim3(4,2,2), 256, 0, stream>>>(
      xb+2560, 3584, Wq_e, 1024, 1024, ws_qpe, 1024,
      xb+2560, 3584, Wq_b, 1024, 1024, ws_qpb, 1024);
  k_energy<<<dim3(8,BB,2), 512, 0, stream>>>(enc, bwd, pk_e, pk_b,
      ws_qpe, ws_qpb, v_e, v_b, smask, ws_atte, ws_attb);
  k_softmax_t<<<dim3(BB,2), 256, 0, stream>>>(ws_atte, ws_attb);
  k_ctx<<<dim3(BB,2,8), 256, 0, stream>>>(enc, bwd, ws_atte, ws_attb, ws_ctxp);
  k_ctxred<<<512, 256, 0, stream>>>(ws_ctxp, ws_ctxe, ws_ctxb);
  k_prep_x2<<<80, 256, 0, stream>>>(tab, y, ws_ctxe, ws_ctxb, xb);
  k_mm64<<<dim3(16,4,2), 256, 0, stream>>>(
      xb,      3584, W_ih, 2560, 2560, ws_gp,             G4,
      xb+2560, 3584, W_hh, 1024, 1024, ws_gp + 4*BB*G4,   G4);
  k_lstm<<<256, 256, 0, stream>>>(ws_gp, b_ih, b_hh, c, out, hb);
  k_vocab2<<<250, 256, 0, stream>>>(hb, Wp, bp, out);
  k_final<<<BB, 1024, 0, stream>>>(ws_ctxe, tab, y, wc, wsv, wy, pgb, out, ws_pgen);
  k_scatter<<<128, 256, 0, stream>>>(sids, ws_atte, ws_pgen, out);
}